// Round 6
// baseline (5283.110 us; speedup 1.0000x reference)
//
#include <hip/hip_runtime.h>
#include <hip/hip_bf16.h>

#define NN 100000
#define NE 1600000
#define NCHUNK 391   // ceil(100000/256)

typedef unsigned short u16;
typedef unsigned int   u32;

__device__ __forceinline__ float bfu(u32 v){ union{u32 i; float f;} w; w.i = v<<16; return w.f; }
__device__ __forceinline__ float bf_lo(u32 u){ return bfu(u & 0xffffu); }
__device__ __forceinline__ float bf_hi(u32 u){ return bfu(u >> 16); }
__device__ __forceinline__ float bf16f(u16 u){ return bfu((u32)u); }
__device__ __forceinline__ u16 f2bf(float f){
    union{float f; u32 i;} w; w.f = f;
    u32 r = (w.i + 0x7fffu + ((w.i >> 16) & 1u)) >> 16;   // RNE
    return (u16)r;
}

template<int IS32>
__device__ __forceinline__ float ldx(const void* p, int i){
    if (IS32) return ((const float*)p)[i];
    else      return bf16f(((const u16*)p)[i]);
}

// ---------------- dtype sniff: fp32 (1) vs bf16 (0) ----------------
__global__ void k_sniff(const u32* __restrict__ x, int* __restrict__ flag){
    __shared__ int cnt[256];
    int t = threadIdx.x;
    int bad = 0;
    for (int i = t; i < 512; i += 256){
        u32 w = x[i];
        u32 lo = w & 0xffffu;
        u32 e = (lo >> 7) & 0xffu;
        bool sane = (lo == 0u) || (lo == 0x8000u) || (e >= 85u && e <= 133u);
        if (!sane) bad++;
    }
    cnt[t] = bad; __syncthreads();
    for (int s = 128; s > 0; s >>= 1){
        if (t < s) cnt[t] += cnt[t+s];
        __syncthreads();
    }
    if (t == 0) flag[0] = (cnt[0] > 100) ? 1 : 0;
}

// ---------------- CSR build (dtype-independent) ----------------

__global__ void k_deg(const int* __restrict__ dst, int* __restrict__ deg){
    int stride = gridDim.x * blockDim.x;
    for (int i = blockIdx.x*blockDim.x + threadIdx.x; i < NE; i += stride){
        int d = dst[i];
        if ((unsigned)d < (unsigned)NN) atomicAdd(&deg[d], 1);
    }
}

__global__ void k_csum(const int* __restrict__ deg, int* __restrict__ csum){
    __shared__ int sdata[256];
    int t = threadIdx.x;
    int idx = blockIdx.x*256 + t;
    sdata[t] = (idx < NN) ? deg[idx] : 0;
    __syncthreads();
    for (int s = 128; s > 0; s >>= 1){
        if (t < s) sdata[t] += sdata[t+s];
        __syncthreads();
    }
    if (t == 0) csum[blockIdx.x] = sdata[0];
}

__global__ void k_scan_chunks(const int* __restrict__ csum, int* __restrict__ coff){
    __shared__ int s[512];
    int t = threadIdx.x;
    int v = (t < NCHUNK) ? csum[t] : 0;
    s[t] = v; __syncthreads();
    int x = v;
    for (int off = 1; off < 512; off <<= 1){
        int y = (t >= off) ? s[t-off] : 0;
        __syncthreads();
        x += y; s[t] = x;
        __syncthreads();
    }
    if (t < NCHUNK) coff[t] = x - v;   // exclusive
}

__global__ void k_rowptr(const int* __restrict__ deg, const int* __restrict__ coff,
                         int* __restrict__ row_ptr){
    __shared__ int s[256];
    int t = threadIdx.x, b = blockIdx.x;
    int idx = b*256 + t;
    int v = (idx < NN) ? deg[idx] : 0;
    s[t] = v; __syncthreads();
    int x = v;
    for (int off = 1; off < 256; off <<= 1){
        int y = (t >= off) ? s[t-off] : 0;
        __syncthreads();
        x += y; s[t] = x;
        __syncthreads();
    }
    if (idx < NN)       row_ptr[idx] = coff[b] + x - v;   // exclusive
    if (idx == NN - 1)  row_ptr[NN]  = coff[b] + x;       // total = NE
}

__global__ void k_scatter(const int* __restrict__ src, const int* __restrict__ dst,
                          const int* __restrict__ row_ptr, int* __restrict__ fill,
                          int2* __restrict__ pair_sorted){
    int stride = gridDim.x * blockDim.x;
    for (int i = blockIdx.x*blockDim.x + threadIdx.x; i < NE; i += stride){
        int d = dst[i];
        if ((unsigned)d >= (unsigned)NN) continue;
        int p = row_ptr[d] + atomicAdd(&fill[d], 1);
        if ((unsigned)p < (unsigned)NE){
            int s = src[i];
            if ((unsigned)s >= (unsigned)NN) s = 0;
            pair_sorted[p] = make_int2(s, i);
        }
    }
}

// ---------------- input projection: h = x @ src_w + src_b (bf16 out) ----------------
template<int IS32>
__global__ __launch_bounds__(256) void k_proj(const void* __restrict__ x,
                                              const void* __restrict__ w,
                                              const void* __restrict__ b,
                                              const int* __restrict__ flg,
                                              u16* __restrict__ h){
    if (flg[0] != IS32) return;
    int lane = threadIdx.x & 63;
    int wid  = (blockIdx.x*256 + threadIdx.x) >> 6;
    int nw   = (gridDim.x*256) >> 6;
    float wr[32];
    #pragma unroll
    for (int k = 0; k < 32; k++) wr[k] = ldx<IS32>(w, k*64 + lane);
    float bias = ldx<IS32>(b, lane);
    for (int node = wid; node < NN; node += nw){
        float acc = bias;
        if (IS32){
            const float* xr = (const float*)x + (size_t)node*32;
            #pragma unroll
            for (int k = 0; k < 32; k++) acc = fmaf(xr[k], wr[k], acc);
        } else {
            const u16* xr = (const u16*)x + (size_t)node*32;
            #pragma unroll
            for (int k = 0; k < 32; k++) acc = fmaf(bf16f(xr[k]), wr[k], acc);
        }
        h[(size_t)node*64 + lane] = f2bf(acc);
    }
}

// ---------------- fused GENConv layer ----------------
template<int IS32>
__global__ __launch_bounds__(256, 3) void k_layer(
    const u16*   __restrict__ h_in,
    const int*   __restrict__ row_ptr,
    const int2*  __restrict__ pair_sorted,
    const void*  __restrict__ ea,
    const void* __restrict__ ew, const void* __restrict__ eb,
    const void* __restrict__ w1, const void* __restrict__ b1,
    const void* __restrict__ g,  const void* __restrict__ bb,
    const void* __restrict__ w2, const void* __restrict__ b2,
    const int* __restrict__ flg,
    u16* __restrict__ h_out)
{
    if (flg[0] != IS32) return;

    __shared__ u32   w1p[64*64];   // packed bf16 pair: lo=w1[k][c], hi=w1[k][c+64]
    __shared__ float w2s[128*64];  // fp32

    int t = threadIdx.x;
    for (int i = t; i < 64*64; i += 256){
        int k = i >> 6, c = i & 63;
        u32 lo, hi;
        if (IS32){
            lo = f2bf(((const float*)w1)[k*128 + c]);
            hi = f2bf(((const float*)w1)[k*128 + c + 64]);
        } else {
            lo = ((const u16*)w1)[k*128 + c];
            hi = ((const u16*)w1)[k*128 + c + 64];
        }
        w1p[i] = lo | (hi << 16);
    }
    for (int i = t; i < 128*64; i += 256) w2s[i] = ldx<IS32>(w2, i);
    __syncthreads();

    int lane = t & 63;
    int wid  = (blockIdx.x*256 + t) >> 6;
    int nw   = (gridDim.x*256) >> 6;

    float ewr[16];
    #pragma unroll
    for (int k = 0; k < 16; k++) ewr[k] = ldx<IS32>(ew, k*64 + lane);
    float ebr = ldx<IS32>(eb, lane);
    const float BNS = 0.9999950000374997f;   // 1/sqrt(1+1e-5)
    float b1a = ldx<IS32>(b1, lane), b1b = ldx<IS32>(b1, lane+64);
    float ga  = ldx<IS32>(g, lane)*BNS,  gb  = ldx<IS32>(g, lane+64)*BNS;
    float bba = ldx<IS32>(bb, lane),     bbb = ldx<IS32>(bb, lane+64);
    float b2r = ldx<IS32>(b2, lane);

    for (int node = wid; node < NN; node += nw){
        int p0 = row_ptr[node], p1 = row_ptr[node+1];
        if (p0 < 0) p0 = 0;
        if (p1 > NE) p1 = NE;
        float m = -1e30f, sw = 0.f, swm = 0.f;
        for (int p = p0; p < p1; ++p){
            int2 pe = pair_sorted[p];
            int s = pe.x;
            if ((unsigned)s >= (unsigned)NN) s = 0;
            unsigned eid = (unsigned)pe.y;
            if (eid >= (unsigned)NE) eid = 0;
            float av[16];
            if (IS32){
                const float4* er = (const float4*)ea + (size_t)eid*4;
                #pragma unroll
                for (int q = 0; q < 4; q++){
                    float4 u = er[q];
                    av[q*4+0]=u.x; av[q*4+1]=u.y; av[q*4+2]=u.z; av[q*4+3]=u.w;
                }
            } else {
                const uint4* er = (const uint4*)ea + (size_t)eid*2;
                #pragma unroll
                for (int q = 0; q < 2; q++){
                    uint4 u = er[q];
                    av[q*8+0]=bf_lo(u.x); av[q*8+1]=bf_hi(u.x);
                    av[q*8+2]=bf_lo(u.y); av[q*8+3]=bf_hi(u.y);
                    av[q*8+4]=bf_lo(u.z); av[q*8+5]=bf_hi(u.z);
                    av[q*8+6]=bf_lo(u.w); av[q*8+7]=bf_hi(u.w);
                }
            }
            float hs = bf16f(h_in[(size_t)s*64 + lane]);
            float e = ebr;
            #pragma unroll
            for (int k = 0; k < 16; k++) e = fmaf(av[k], ewr[k], e);
            float v = fmaxf(hs + e, 0.f) + 1e-7f;     // msg
            float nm = fmaxf(m, v);
            float al = __expf(m - nm);                // 0 on first edge (m=-1e30)
            float pw = __expf(v - nm);
            sw  = sw*al + pw;
            swm = swm*al + pw*v;
            m = nm;
        }
        float agg = (sw > 0.f) ? (swm / sw) : 0.f;
        float out = agg + bf16f(h_in[(size_t)node*64 + lane]);

        // MLP: 64 -> 128 (BN + relu) -> 64, then outer relu
        float acc1 = b1a, acc2 = b1b;
        #pragma unroll
        for (int k = 0; k < 64; k++){
            float ok = __shfl(out, k, 64);
            u32 wp = w1p[k*64 + lane];
            acc1 = fmaf(ok, bf_lo(wp), acc1);
            acc2 = fmaf(ok, bf_hi(wp), acc2);
        }
        float hh1 = fmaxf(fmaf(acc1, ga, bba), 0.f);
        float hh2 = fmaxf(fmaf(acc2, gb, bbb), 0.f);
        float acc = b2r;
        #pragma unroll
        for (int j = 0; j < 64; j++){
            float a1 = __shfl(hh1, j, 64);
            float a2 = __shfl(hh2, j, 64);
            acc = fmaf(a1, w2s[j*64 + lane], acc);
            acc = fmaf(a2, w2s[(j+64)*64 + lane], acc);
        }
        h_out[(size_t)node*64 + lane] = f2bf(fmaxf(acc, 0.f));
    }
}

// ---------------- head: out = concat(h, gf) @ head_w + head_b  (FP32 OUT) ----------------
template<int IS32>
__global__ __launch_bounds__(256) void k_head(const u16* __restrict__ h,
                                              const void* __restrict__ gf,
                                              const int* __restrict__ ngp,
                                              const void* __restrict__ hw,
                                              const void* __restrict__ hb,
                                              const int* __restrict__ flg,
                                              float* __restrict__ out){
    if (flg[0] != IS32) return;
    int lane = threadIdx.x & 63;
    int wid  = (blockIdx.x*256 + threadIdx.x) >> 6;
    int nw   = (gridDim.x*256) >> 6;
    float wc  = ldx<IS32>(hw, lane);
    float w64 = ldx<IS32>(hw, 64), w65 = ldx<IS32>(hw, 65);
    float bias = ldx<IS32>(hb, 0);
    int ng  = ngp[0];
    if (ng <= 0) ng = 1;
    int npg = NN / ng;
    if (npg <= 0) npg = 1;
    for (int node = wid; node < NN; node += nw){
        float v = bf16f(h[(size_t)node*64 + lane]) * wc;
        #pragma unroll
        for (int off = 32; off > 0; off >>= 1) v += __shfl_xor(v, off, 64);
        if (lane == 0){
            int gidx = node / npg, r = node - gidx*npg;
            float g0 = ldx<IS32>(gf, (gidx*2 + 0)*npg + r);
            float g1 = ldx<IS32>(gf, (gidx*2 + 1)*npg + r);
            out[node] = v + g0*w64 + g1*w65 + bias;   // fp32 store — reference output dtype
        }
    }
}

// ---------------- launch ----------------
extern "C" void kernel_launch(void* const* d_in, const int* in_sizes, int n_in,
                              void* d_out, int out_size, void* d_ws, size_t ws_size,
                              hipStream_t stream){
    const void* x    = d_in[0];
    const int*  ei   = (const int*)d_in[1];          // [2, NE]: row0=src, row1=dst
    const void* ea   = d_in[2];
    const int*  ngp  = (const int*)d_in[3];
    const void* gf   = d_in[4];
    const void* srcw = d_in[5];
    const void* srcb = d_in[6];
    const void* L[16];
    for (int i = 0; i < 16; i++) L[i] = d_in[7 + i];
    const void* headw = d_in[23];
    const void* headb = d_in[24];

    char* ws = (char*)d_ws;
    size_t off = 0;
    auto alloc = [&](size_t bytes) -> void* {
        void* p = ws + off;
        off += (bytes + 255) & ~size_t(255);
        return p;
    };
    u16* hA          = (u16*)  alloc((size_t)NN*64*2);    // 12.8 MB
    u16* hB          = (u16*)  alloc((size_t)NN*64*2);    // 12.8 MB
    int* row_ptr     = (int*)  alloc((size_t)(NN+1)*4);
    int* cnt         = (int*)  alloc((size_t)2*NN*4);     // deg | fill
    int* deg  = cnt;
    int* fill = cnt + NN;
    int* csum        = (int*)  alloc((size_t)NCHUNK*4);
    int* coff        = (int*)  alloc((size_t)NCHUNK*4);
    int* flg         = (int*)  alloc(256);
    int2* pair_sorted= (int2*) alloc((size_t)NE*8);       // 12.8 MB
    // total ~= 39.7 MB

    hipMemsetAsync(cnt, 0, (size_t)2*NN*4, stream);

    const int* e_src = ei;
    const int* e_dst = ei + NE;

    k_sniff      <<<1, 256, 0, stream>>>((const u32*)x, flg);
    k_deg        <<<1024, 256, 0, stream>>>(e_dst, deg);
    k_csum       <<<NCHUNK, 256, 0, stream>>>(deg, csum);
    k_scan_chunks<<<1, 512, 0, stream>>>(csum, coff);
    k_rowptr     <<<NCHUNK, 256, 0, stream>>>(deg, coff, row_ptr);
    k_scatter    <<<1024, 256, 0, stream>>>(e_src, e_dst, row_ptr, fill, pair_sorted);

    k_proj<1>    <<<512, 256, 0, stream>>>(x, srcw, srcb, flg, hA);
    k_proj<0>    <<<512, 256, 0, stream>>>(x, srcw, srcb, flg, hA);

    k_layer<1>   <<<1024, 256, 0, stream>>>(hA, row_ptr, pair_sorted, ea,
                    L[0], L[1], L[2], L[3], L[4], L[5], L[6], L[7], flg, hB);
    k_layer<0>   <<<1024, 256, 0, stream>>>(hA, row_ptr, pair_sorted, ea,
                    L[0], L[1], L[2], L[3], L[4], L[5], L[6], L[7], flg, hB);

    k_layer<1>   <<<1024, 256, 0, stream>>>(hB, row_ptr, pair_sorted, ea,
                    L[8], L[9], L[10], L[11], L[12], L[13], L[14], L[15], flg, hA);
    k_layer<0>   <<<1024, 256, 0, stream>>>(hB, row_ptr, pair_sorted, ea,
                    L[8], L[9], L[10], L[11], L[12], L[13], L[14], L[15], flg, hA);

    k_head<1>    <<<512, 256, 0, stream>>>(hA, gf, ngp, headw, headb, flg, (float*)d_out);
    k_head<0>    <<<512, 256, 0, stream>>>(hA, gf, ngp, headw, headb, flg, (float*)d_out);
}